// Round 17
// baseline (228.460 us; speedup 1.0000x reference)
//
#include <hip/hip_runtime.h>
#include <cstdint>

#define C_ 128
#define L_ 16
#define G_ 4
#define H_ 56
#define W_ 56
#define HW_ 3136
#define CH_ 2                      // channels per chunk
#define NCK_ 16                    // chunks
#define NR_ 5                      // halo rows per wave (r = 2w .. 2w+4)
#define WBUF_F 768                 // 12 rows x 64 floats (rows 10,11 dummy)
#define WL_F 2048                  // weights [c(32)][dy(8)][dx(8)]
#define LDS_F (WL_F + 4 * 2 * WBUF_F)  // 8192 floats = 32768 B

typedef float f4 __attribute__((ext_vector_type(4)));
typedef float f2 __attribute__((ext_vector_type(2)));
typedef __attribute__((address_space(3))) uint32_t lds_u32;
typedef const __attribute__((address_space(1))) uint32_t glb_u32;

// r16 structure (no main-loop barriers, per-wave branchless dbuf DMA staging,
// exact vmcnt(4)) + PACKED-FP32 inner loop:
//   acc2[7][4] f2 pairs over p; per cell v_pk_mul_f32 (x1-pair x rr-pair) +
//   v_pk_fma_f32 with weight broadcast via op_sel (lo/hi of the aligned
//   weight pair replicated -> no broadcast movs). Odd-offset rr pairs
//   (needed for even dx; 64-bit VGPR operands are even-aligned) are
//   materialized once per ci as rrO[7] (14 movs). Main-loop VALU insts/MAC:
//   2.0 -> ~1.3, FMA chain depth halved. This targets the r16 plateau where
//   VALUBusy 45% WAS the issue count, not stalls.
__global__ __launch_bounds__(256, 2)
void wcorr(const float* __restrict__ x, const float* __restrict__ wgt,
           float* __restrict__ out, const float* __restrict__ zsrc) {
  __shared__ float lds[LDS_F];

  int bid = blockIdx.x;
  // bijective XCD swizzle: nwg = 7168 = 8*896; htile fastest (halo-row reuse)
  int wid = (bid & 7) * 896 + (bid >> 3);
  int htile = wid % 14;
  int rest = wid / 14;             // (b*4+g)*16 + t
  int t = rest & 15;
  int bg = rest >> 4;
  int g = bg & 3;
  int b = bg >> 2;
  int h0 = htile * 4;

  int tid = threadIdx.x;
  int lane = tid & 63;
  int wvu = __builtin_amdgcn_readfirstlane(tid >> 6);  // wave 0..3 (uniform)
  int tx = tid & 7;
  int slot = tid >> 3;
  int h = slot & 3;
  int dy = slot >> 2;              // wave w holds dy in {2w, 2w+1}
  bool active = (dy < 7) && (tx < 7);
  int dyc = dy < 7 ? dy : 6;
  int txc = tx < 7 ? tx : 6;
  int r = h + dyc;                 // global halo row 0..9
  int lr = r - 2 * wvu;            // local row in wave tile, 0..4
  int t1 = t > 0 ? t - 1 : 0;
  int w0 = 8 * txc;

  const size_t cstride = (size_t)L_ * HW_;
  const float* xg = x + ((size_t)b * C_ + (size_t)g * 32) * cstride;

  // branchless per-call staging pointers (k-invariant selection):
  auto mkstage = [&](int j, const float*& sp, ptrdiff_t& inc) {
    int tau = lane + j * 64;
    int row = tau >> 4;
    int ci = (row >= NR_) ? 1 : 0;
    int lrr = row - ci * NR_;
    int rg = 2 * wvu + lrr;
    int vb = (tau & 15) ^ (rg & 7);
    int hh = h0 - 3 + rg;
    bool ok = (row < 2 * NR_) && (vb >= 1) && (vb <= 14)
              && (hh >= 0) && (hh < H_);
    sp = ok ? (xg + (size_t)ci * cstride + (size_t)t * HW_
                  + hh * W_ + (vb * 4 - 4))
            : (zsrc + (lane & 15) * 4);
    inc = ok ? (ptrdiff_t)(CH_ * cstride) : 0;
  };
  const float *sp0, *sp1, *sp2;
  ptrdiff_t in0, in1, in2;
  mkstage(0, sp0, in0);
  mkstage(1, sp1, in1);
  mkstage(2, sp2, in2);

  // prologue: stage chunk 0 -> buf 0 (drained by the weights barrier below)
  {
    float* db = &lds[WL_F + (wvu * 2) * WBUF_F];
    __builtin_amdgcn_global_load_lds((glb_u32*)sp0, (lds_u32*)(db + 0), 16, 0, 0);
    __builtin_amdgcn_global_load_lds((glb_u32*)sp1, (lds_u32*)(db + 256), 16, 0, 0);
    __builtin_amdgcn_global_load_lds((glb_u32*)sp2, (lds_u32*)(db + 512), 16, 0, 0);
    sp0 += in0; sp1 += in1; sp2 += in2;
  }

  // stage weights transposed [c][dy][8], 1/32 folded (pad dx=7 -> 0)
  {
    const float sc = 1.0f / 32.0f;
    const float* wsrc = wgt + (size_t)(g * 32) * (L_ * 49) + t * 49;
    #pragma unroll
    for (int j = 0; j < 8; ++j) {
      int idx = tid + j * 256;
      int c = idx >> 6;
      int rem = idx & 63;
      int dyy = rem >> 3, dxx = rem & 7;
      float v = 0.0f;
      if (dyy < 7 && dxx < 7)
        v = wsrc[(size_t)c * (L_ * 49) + dyy * 7 + dxx] * sc;
      lds[idx] = v;
    }
  }

  const float* x1c0 = xg + (size_t)t1 * HW_ + (size_t)(h0 + h) * W_ + w0;
  const float* x1c1 = x1c0 + cstride;

  f2 acc2[7][4];
  #pragma unroll
  for (int i = 0; i < 7; ++i)
    #pragma unroll
    for (int j = 0; j < 4; ++j) acc2[i][j] = (f2)(0.0f);

  __syncthreads();   // weights visible; drains prologue stage; ONLY barrier

  int s = r & 7;
  #pragma unroll 1
  for (int k = 0; k < NCK_; ++k) {
    int kb = k & 1;
    int c0 = k * CH_;
    // x1 loads first: queue = [stage(k):3][x1:4]
    f4 a00 = *(const f4*)(x1c0);
    f4 a01 = *(const f4*)(x1c0 + 4);
    f4 a10 = *(const f4*)(x1c1);
    f4 a11 = *(const f4*)(x1c1 + 4);
    x1c0 += CH_ * cstride;
    x1c1 += CH_ * cstride;

    __builtin_amdgcn_sched_barrier(0);
    asm volatile("s_waitcnt vmcnt(4)" ::: "memory");  // stage(k) landed exactly
    __builtin_amdgcn_sched_barrier(0);

    const float* base = &lds[WL_F + (wvu * 2 + kb) * WBUF_F];
    const f4* xsrow0 = (const f4*)(base + lr * 64);
    const f4* xsrow1 = (const f4*)(base + (NR_ + lr) * 64);
    f4 q00 = xsrow0[(2 * txc + 0) ^ s];
    f4 q01 = xsrow0[(2 * txc + 1) ^ s];
    f4 q02 = xsrow0[(2 * txc + 2) ^ s];
    f4 q03 = xsrow0[(2 * txc + 3) ^ s];
    f4 q10 = xsrow1[(2 * txc + 0) ^ s];
    f4 q11 = xsrow1[(2 * txc + 1) ^ s];
    f4 q12 = xsrow1[(2 * txc + 2) ^ s];
    f4 q13 = xsrow1[(2 * txc + 3) ^ s];
    const f4* wl0 = (const f4*)&lds[(c0 + 0) * 64 + dyc * 8];
    const f4* wl1 = (const f4*)&lds[(c0 + 1) * 64 + dyc * 8];
    f4 wa0 = wl0[0], wa1 = wl0[1];
    f4 wb0 = wl1[0], wb1 = wl1[1];

    if (k + 1 < NCK_) {            // prefetch chunk k+1 -> other buffer
      float* db = &lds[WL_F + (wvu * 2 + (kb ^ 1)) * WBUF_F];
      __builtin_amdgcn_global_load_lds((glb_u32*)sp0, (lds_u32*)(db + 0), 16, 0, 0);
      __builtin_amdgcn_global_load_lds((glb_u32*)sp1, (lds_u32*)(db + 256), 16, 0, 0);
      __builtin_amdgcn_global_load_lds((glb_u32*)sp2, (lds_u32*)(db + 512), 16, 0, 0);
      sp0 += in0; sp1 += in1; sp2 += in2;
    }

    __builtin_amdgcn_s_setprio(1);
    #pragma unroll
    for (int ci = 0; ci < CH_; ++ci) {
      f4 Q0 = ci ? q10 : q00, Q1 = ci ? q11 : q01;
      f4 Q2 = ci ? q12 : q02, Q3 = ci ? q13 : q03;
      f4 W0 = ci ? wb0 : wa0, W1 = ci ? wb1 : wa1;
      f4 A0 = ci ? a10 : a00, A1 = ci ? a11 : a01;
      float rrf[16] = {Q0.x, Q0.y, Q0.z, Q0.w, Q1.x, Q1.y, Q1.z, Q1.w,
                       Q2.x, Q2.y, Q2.z, Q2.w, Q3.x, Q3.y, Q3.z, Q3.w};
      // aligned even pairs (register aliases) and odd-offset pairs (movs)
      f2 rrE[8] = {{rrf[0], rrf[1]}, {rrf[2], rrf[3]}, {rrf[4], rrf[5]},
                   {rrf[6], rrf[7]}, {rrf[8], rrf[9]}, {rrf[10], rrf[11]},
                   {rrf[12], rrf[13]}, {rrf[14], rrf[15]}};
      f2 rrO[7] = {{rrf[1], rrf[2]}, {rrf[3], rrf[4]}, {rrf[5], rrf[6]},
                   {rrf[7], rrf[8]}, {rrf[9], rrf[10]}, {rrf[11], rrf[12]},
                   {rrf[13], rrf[14]}};
      f2 x1E[4] = {{A0.x, A0.y}, {A0.z, A0.w}, {A1.x, A1.y}, {A1.z, A1.w}};
      f2 wE[4] = {{W0.x, W0.y}, {W0.z, W0.w}, {W1.x, W1.y}, {W1.z, W1.w}};
      // cell (dx, j): p = 2j,2j+1; needs rr[q], rr[q+1], q = 2j+dx+1.
      // dx odd  -> q even -> rrE[j + (dx+1)/2]; w = wE[dx>>1].hi (op_sel 1)
      // dx even -> q odd  -> rrO[j + dx/2];     w = wE[dx>>1].lo (op_sel 0)
      #pragma unroll
      for (int dxx = 0; dxx < 7; ++dxx) {
        #pragma unroll
        for (int j = 0; j < 4; ++j) {
          f2 R = (dxx & 1) ? rrE[j + ((dxx + 1) >> 1)] : rrO[j + (dxx >> 1)];
          f2 m;
          asm("v_pk_mul_f32 %0, %1, %2" : "=v"(m) : "v"(x1E[j]), "v"(R));
          if (dxx & 1)
            asm("v_pk_fma_f32 %0, %1, %2, %0 op_sel:[1,0,0] op_sel_hi:[1,1,1]"
                : "+v"(acc2[dxx][j]) : "v"(wE[dxx >> 1]), "v"(m));
          else
            asm("v_pk_fma_f32 %0, %1, %2, %0 op_sel:[0,0,0] op_sel_hi:[0,1,1]"
                : "+v"(acc2[dxx][j]) : "v"(wE[dxx >> 1]), "v"(m));
        }
      }
    }
    __builtin_amdgcn_s_setprio(0);
  }

  if (active) {
    #pragma unroll
    for (int dxx = 0; dxx < 7; ++dxx) {
      int och = (dy * 7 + dxx) * G_ + g;
      float* op = out + (((size_t)b * 196 + och) * L_ + t) * (size_t)HW_
                      + (size_t)(h0 + h) * W_ + w0;
      f4 o0 = {acc2[dxx][0].x, acc2[dxx][0].y, acc2[dxx][1].x, acc2[dxx][1].y};
      f4 o1 = {acc2[dxx][2].x, acc2[dxx][2].y, acc2[dxx][3].x, acc2[dxx][3].y};
      __builtin_nontemporal_store(o0, (f4*)op);
      __builtin_nontemporal_store(o1, (f4*)(op + 4));
    }
  }
}

extern "C" void kernel_launch(void* const* d_in, const int* in_sizes, int n_in,
                              void* d_out, int out_size, void* d_ws, size_t ws_size,
                              hipStream_t stream) {
  const float* x = (const float*)d_in[0];
  const float* w = (const float*)d_in[1];
  float* o = (float*)d_out;
  // 256 B zeros region for redirected (pad/OOB/dummy) staging lanes
  hipMemsetAsync(d_ws, 0, 256, stream);
  dim3 grid(7168), block(256);
  hipLaunchKernelGGL(wcorr, grid, block, 0, stream, x, w, o, (const float*)d_ws);
}

// Round 18
// 222.087 us; speedup vs baseline: 1.0287x; 1.0287x over previous
//
#include <hip/hip_runtime.h>
#include <cstdint>

#define C_ 128
#define L_ 16
#define G_ 4
#define H_ 56
#define W_ 56
#define HW_ 3136
#define CH_ 2                      // channels per chunk
#define NCK_ 16                    // chunks
#define NR_ 5                      // halo rows per wave (r = 2w .. 2w+4)
#define WBUF_F 768                 // 12 rows x 64 floats (rows 10,11 dummy)
#define LDS_F (4 * 2 * WBUF_F)     // 6144 floats = 24576 B -> 6 blocks/CU

typedef float f4 __attribute__((ext_vector_type(4)));
typedef __attribute__((address_space(3))) uint32_t lds_u32;
typedef const __attribute__((address_space(1))) uint32_t glb_u32;

// r16 structure (per-wave branchless dbuf DMA staging, exact vmcnt(4),
// scalar FMA — r17's pk-f32 reverted: half-rate on CDNA4) with weights moved
// OFF LDS entirely:
//  - weights via wave-uniform scalar loads (s_load on the SMEM pipe): dy is
//    2-valued per wave -> load both rows, select with v_cndmask (14/chunk).
//    dy==7 row clamped to 6 (page safety; those lanes are store-masked).
//  - LDS = 24576 B -> 6 blocks/CU (was 5): +20% TLP.
//  - LDS reads per chunk: 10 -> 8 b128 (-20% LDS-pipe demand).
//  - ZERO barriers: no weights prologue; branchless DMA writes every slot
//    (zsrc zeros for pad/OOB/dummy); prologue drain covered by vmcnt(4).
__global__ __launch_bounds__(256, 2)
void wcorr(const float* __restrict__ x, const float* __restrict__ wgt,
           float* __restrict__ out, const float* __restrict__ zsrc) {
  __shared__ float lds[LDS_F];

  int bid = blockIdx.x;
  // bijective XCD swizzle: nwg = 7168 = 8*896; htile fastest (halo-row reuse)
  int wid = (bid & 7) * 896 + (bid >> 3);
  int htile = wid % 14;
  int rest = wid / 14;             // (b*4+g)*16 + t
  int t = rest & 15;
  int bg = rest >> 4;
  int g = bg & 3;
  int b = bg >> 2;
  int h0 = htile * 4;

  int tid = threadIdx.x;
  int lane = tid & 63;
  int wvu = __builtin_amdgcn_readfirstlane(tid >> 6);  // wave 0..3 (uniform)
  int tx = tid & 7;
  int slot = tid >> 3;
  int h = slot & 3;
  int dy = slot >> 2;              // wave w holds dy in {2w, 2w+1}
  bool active = (dy < 7) && (tx < 7);
  bool hi = (lane >= 32);          // dy parity within the wave
  int dyc = dy < 7 ? dy : 6;
  int txc = tx < 7 ? tx : 6;
  int r = h + dyc;                 // global halo row 0..9
  int lr = r - 2 * wvu;            // local row in wave tile, 0..4
  int t1 = t > 0 ? t - 1 : 0;
  int w0 = 8 * txc;

  const size_t cstride = (size_t)L_ * HW_;
  const float* xg = x + ((size_t)b * C_ + (size_t)g * 32) * cstride;

  // branchless per-call staging pointers (k-invariant selection):
  auto mkstage = [&](int j, const float*& sp, ptrdiff_t& inc) {
    int tau = lane + j * 64;
    int row = tau >> 4;
    int ci = (row >= NR_) ? 1 : 0;
    int lrr = row - ci * NR_;
    int rg = 2 * wvu + lrr;
    int vb = (tau & 15) ^ (rg & 7);
    int hh = h0 - 3 + rg;
    bool ok = (row < 2 * NR_) && (vb >= 1) && (vb <= 14)
              && (hh >= 0) && (hh < H_);
    sp = ok ? (xg + (size_t)ci * cstride + (size_t)t * HW_
                  + hh * W_ + (vb * 4 - 4))
            : (zsrc + (lane & 15) * 4);
    inc = ok ? (ptrdiff_t)(CH_ * cstride) : 0;
  };
  const float *sp0, *sp1, *sp2;
  ptrdiff_t in0, in1, in2;
  mkstage(0, sp0, in0);
  mkstage(1, sp1, in1);
  mkstage(2, sp2, in2);

  // prologue: stage chunk 0 -> buf 0 (drained by vmcnt(4) at iter 0)
  {
    float* db = &lds[(wvu * 2) * WBUF_F];
    __builtin_amdgcn_global_load_lds((glb_u32*)sp0, (lds_u32*)(db + 0), 16, 0, 0);
    __builtin_amdgcn_global_load_lds((glb_u32*)sp1, (lds_u32*)(db + 256), 16, 0, 0);
    __builtin_amdgcn_global_load_lds((glb_u32*)sp2, (lds_u32*)(db + 512), 16, 0, 0);
    sp0 += in0; sp1 += in1; sp2 += in2;
  }

  // wave-uniform weight row bases (SMEM path); dyB clamped for page safety
  int dyA = 2 * wvu;
  int dyB = (2 * wvu + 1 < 7) ? (2 * wvu + 1) : 6;
  const float* wgtg = wgt + (size_t)(g * 32) * (L_ * 49) + t * 49;

  const float* x1c0 = xg + (size_t)t1 * HW_ + (size_t)(h0 + h) * W_ + w0;
  const float* x1c1 = x1c0 + cstride;

  float acc[7][8];
  #pragma unroll
  for (int i = 0; i < 7; ++i)
    #pragma unroll
    for (int p = 0; p < 8; ++p) acc[i][p] = 0.0f;

  int s = r & 7;
  #pragma unroll 1
  for (int k = 0; k < NCK_; ++k) {
    int kb = k & 1;
    int c0 = k * CH_;
    // x1 loads first: queue = [stage(k):3][x1:4]
    f4 a00 = *(const f4*)(x1c0);
    f4 a01 = *(const f4*)(x1c0 + 4);
    f4 a10 = *(const f4*)(x1c1);
    f4 a11 = *(const f4*)(x1c1 + 4);
    x1c0 += CH_ * cstride;
    x1c1 += CH_ * cstride;

    __builtin_amdgcn_sched_barrier(0);
    asm volatile("s_waitcnt vmcnt(4)" ::: "memory");  // stage(k) landed exactly
    __builtin_amdgcn_sched_barrier(0);

    const float* base = &lds[(wvu * 2 + kb) * WBUF_F];
    const f4* xsrow0 = (const f4*)(base + lr * 64);
    const f4* xsrow1 = (const f4*)(base + (NR_ + lr) * 64);
    f4 q00 = xsrow0[(2 * txc + 0) ^ s];
    f4 q01 = xsrow0[(2 * txc + 1) ^ s];
    f4 q02 = xsrow0[(2 * txc + 2) ^ s];
    f4 q03 = xsrow0[(2 * txc + 3) ^ s];
    f4 q10 = xsrow1[(2 * txc + 0) ^ s];
    f4 q11 = xsrow1[(2 * txc + 1) ^ s];
    f4 q12 = xsrow1[(2 * txc + 2) ^ s];
    f4 q13 = xsrow1[(2 * txc + 3) ^ s];

    // weights: wave-uniform scalar loads (SMEM) + per-lane-half select
    const float* wc0 = wgtg + (size_t)c0 * (L_ * 49);
    const float* wc1 = wc0 + (L_ * 49);
    float w70[7], w71[7];
    #pragma unroll
    for (int d = 0; d < 7; ++d) {
      float a0w = wc0[dyA * 7 + d], b0w = wc0[dyB * 7 + d];
      float a1w = wc1[dyA * 7 + d], b1w = wc1[dyB * 7 + d];
      w70[d] = hi ? b0w : a0w;
      w71[d] = hi ? b1w : a1w;
    }

    if (k + 1 < NCK_) {            // prefetch chunk k+1 -> other buffer
      float* db = &lds[(wvu * 2 + (kb ^ 1)) * WBUF_F];
      __builtin_amdgcn_global_load_lds((glb_u32*)sp0, (lds_u32*)(db + 0), 16, 0, 0);
      __builtin_amdgcn_global_load_lds((glb_u32*)sp1, (lds_u32*)(db + 256), 16, 0, 0);
      __builtin_amdgcn_global_load_lds((glb_u32*)sp2, (lds_u32*)(db + 512), 16, 0, 0);
      sp0 += in0; sp1 += in1; sp2 += in2;
    }

    __builtin_amdgcn_s_setprio(1);
    #pragma unroll
    for (int ci = 0; ci < CH_; ++ci) {
      f4 Q0 = ci ? q10 : q00, Q1 = ci ? q11 : q01;
      f4 Q2 = ci ? q12 : q02, Q3 = ci ? q13 : q03;
      f4 A0 = ci ? a10 : a00, A1 = ci ? a11 : a01;
      const float* w7 = ci ? w71 : w70;
      float rr_[16] = {Q0.x, Q0.y, Q0.z, Q0.w, Q1.x, Q1.y, Q1.z, Q1.w,
                       Q2.x, Q2.y, Q2.z, Q2.w, Q3.x, Q3.y, Q3.z, Q3.w};
      float x1v[8] = {A0.x, A0.y, A0.z, A0.w, A1.x, A1.y, A1.z, A1.w};
      #pragma unroll
      for (int dxx = 0; dxx < 7; ++dxx) {
        #pragma unroll
        for (int p = 0; p < 8; ++p) {
          acc[dxx][p] = fmaf(w7[dxx], x1v[p] * rr_[p + dxx + 1], acc[dxx][p]);
        }
      }
    }
    __builtin_amdgcn_s_setprio(0);
  }

  if (active) {
    const float sc = 1.0f / 32.0f;
    #pragma unroll
    for (int dxx = 0; dxx < 7; ++dxx) {
      int och = (dy * 7 + dxx) * G_ + g;
      float* op = out + (((size_t)b * 196 + och) * L_ + t) * (size_t)HW_
                      + (size_t)(h0 + h) * W_ + w0;
      f4 o0 = {acc[dxx][0] * sc, acc[dxx][1] * sc,
               acc[dxx][2] * sc, acc[dxx][3] * sc};
      f4 o1 = {acc[dxx][4] * sc, acc[dxx][5] * sc,
               acc[dxx][6] * sc, acc[dxx][7] * sc};
      __builtin_nontemporal_store(o0, (f4*)op);
      __builtin_nontemporal_store(o1, (f4*)(op + 4));
    }
  }
}

extern "C" void kernel_launch(void* const* d_in, const int* in_sizes, int n_in,
                              void* d_out, int out_size, void* d_ws, size_t ws_size,
                              hipStream_t stream) {
  const float* x = (const float*)d_in[0];
  const float* w = (const float*)d_in[1];
  float* o = (float*)d_out;
  // 256 B zeros region for redirected (pad/OOB/dummy) staging lanes
  hipMemsetAsync(d_ws, 0, 256, stream);
  dim3 grid(7168), block(256);
  hipLaunchKernelGGL(wcorr, grid, block, 0, stream, x, w, o, (const float*)d_ws);
}